// Round 1
// baseline (493.636 us; speedup 1.0000x reference)
//
#include <hip/hip_runtime.h>
#include <math.h>

// ChebConv GNN: N=50000 nodes, E=800000 edges, F=H=64, C=10.
// Pipeline:
//   deg[i] = #edges with src==i ; dis = deg>0 ? rsqrt(deg) : 0
//   w[e] = -(dis[src]*dis[dst])
//   h   = relu(x @ W1_0 + b1)
//   lap[dst] += w[e]*h[src]           (edge scatter, dominant cost)
//   h2  = relu(h @ W2_0 + lap @ W2_1 + b2)
//   out = log_softmax((h2 + h) @ Wl + bl)

__global__ __launch_bounds__(256) void deg_kernel(const int* __restrict__ src,
                                                  float* __restrict__ deg, int E) {
    int e = blockIdx.x * blockDim.x + threadIdx.x;
    if (e < E) atomicAdd(&deg[src[e]], 1.0f);
}

__global__ __launch_bounds__(256) void dis_kernel(float* __restrict__ deg, int n) {
    int i = blockIdx.x * blockDim.x + threadIdx.x;
    if (i < n) {
        float d = deg[i];
        deg[i] = (d > 0.0f) ? rsqrtf(d) : 0.0f;
    }
}

// h = relu(x @ W + b), x:[n,64], W:[64,64]. 1 wave = 1 row, lane = out col.
__global__ __launch_bounds__(256) void gemm1_kernel(const float* __restrict__ x,
                                                    const float* __restrict__ W,
                                                    const float* __restrict__ b,
                                                    float* __restrict__ h, int n) {
    __shared__ float sW[64 * 64];
    int tid = threadIdx.x;
    for (int i = tid; i < 64 * 64; i += 256) sW[i] = W[i];
    __syncthreads();
    int wv = tid >> 6, c = tid & 63;
    float bc = b[c];
    int row0 = blockIdx.x * 32 + wv * 8;
    for (int i = 0; i < 8; ++i) {
        int row = row0 + i;
        if (row >= n) break;
        float xv = x[(size_t)row * 64 + c];
        float acc = bc;
#pragma unroll
        for (int k = 0; k < 64; ++k)
            acc += __shfl(xv, k) * sW[k * 64 + c];
        h[(size_t)row * 64 + c] = fmaxf(acc, 0.0f);
    }
}

// lap[dst] += -(dis[src]*dis[dst]) * h[src]; 1 wave = 1 edge, lane = feature.
__global__ __launch_bounds__(256) void scatter_kernel(const int* __restrict__ ei,
                                                      const float* __restrict__ dis,
                                                      const float* __restrict__ h,
                                                      float* __restrict__ lap, int E) {
    int wv = threadIdx.x >> 6, c = threadIdx.x & 63;
    int e0 = blockIdx.x * 16 + wv * 4;
    for (int i = 0; i < 4; ++i) {
        int e = e0 + i;
        if (e < E) {
            int s = ei[e];
            int d = ei[E + e];
            float we = -(dis[s] * dis[d]);
            float val = we * h[(size_t)s * 64 + c];
            atomicAdd(&lap[(size_t)d * 64 + c], val);
        }
    }
}

// h2 = relu(h@W20 + lap@W21 + b2); out = log_softmax((h2+h)@Wl + bl)
__global__ __launch_bounds__(256) void fused2_kernel(const float* __restrict__ h,
                                                     const float* __restrict__ lap,
                                                     const float* __restrict__ W20,
                                                     const float* __restrict__ W21,
                                                     const float* __restrict__ b2,
                                                     const float* __restrict__ Wl,
                                                     const float* __restrict__ bl,
                                                     float* __restrict__ out, int n) {
    __shared__ float sW20[64 * 64];
    __shared__ float sW21[64 * 64];
    __shared__ float sWl[64 * 10];
    int tid = threadIdx.x;
    for (int i = tid; i < 64 * 64; i += 256) {
        sW20[i] = W20[i];
        sW21[i] = W21[i];
    }
    for (int i = tid; i < 64 * 10; i += 256) sWl[i] = Wl[i];
    __syncthreads();
    int wv = tid >> 6, c = tid & 63;
    float b2c = b2[c];
    int row0 = blockIdx.x * 32 + wv * 8;
    for (int i = 0; i < 8; ++i) {
        int row = row0 + i;
        if (row >= n) break;
        float hv = h[(size_t)row * 64 + c];
        float lv = lap[(size_t)row * 64 + c];
        float acc = b2c;
#pragma unroll
        for (int k = 0; k < 64; ++k) {
            acc += __shfl(hv, k) * sW20[k * 64 + c];
            acc += __shfl(lv, k) * sW21[k * 64 + c];
        }
        float h2 = fmaxf(acc, 0.0f) + hv;  // + residual (x_res = h)

        // out[row][j] = sum_c h2[c]*Wl[c][j] + bl[j], then log_softmax over j
        float m = -1e30f;
        float myout = 0.0f;
#pragma unroll
        for (int j = 0; j < 10; ++j) {
            float p = h2 * sWl[c * 10 + j];
#pragma unroll
            for (int mk = 1; mk < 64; mk <<= 1) p += __shfl_xor(p, mk);
            p += bl[j];
            if (c == j) myout = p;
            m = fmaxf(m, p);  // p is wave-uniform after butterfly
        }
        float ev = (c < 10) ? expf(myout - m) : 0.0f;
#pragma unroll
        for (int mk = 1; mk < 64; mk <<= 1) ev += __shfl_xor(ev, mk);
        if (c < 10) out[(size_t)row * 10 + c] = myout - m - logf(ev);
    }
}

extern "C" void kernel_launch(void* const* d_in, const int* in_sizes, int n_in,
                              void* d_out, int out_size, void* d_ws, size_t ws_size,
                              hipStream_t stream) {
    const float* x   = (const float*)d_in[0];
    const int*   ei  = (const int*)d_in[1];
    const float* W1  = (const float*)d_in[2];
    const float* b1  = (const float*)d_in[3];
    const float* W20 = (const float*)d_in[4];
    const float* W21 = (const float*)d_in[5];
    const float* b2  = (const float*)d_in[6];
    const float* Wl  = (const float*)d_in[7];
    const float* bl  = (const float*)d_in[8];
    float* out = (float*)d_out;

    int n = in_sizes[0] / 64;   // 50000
    int E = in_sizes[1] / 2;    // 800000

    char* ws = (char*)d_ws;
    float* deg = (float*)ws;  // n floats; becomes dis in-place
    size_t off1 = ((size_t)n * 4 + 255) & ~(size_t)255;
    float* h = (float*)(ws + off1);  // n*64 floats
    size_t off2 = off1 + ((((size_t)n * 64 * 4) + 255) & ~(size_t)255);
    float* lap = (float*)(ws + off2);  // n*64 floats

    hipMemsetAsync(deg, 0, (size_t)n * 4, stream);
    hipMemsetAsync(lap, 0, (size_t)n * 64 * 4, stream);

    deg_kernel<<<(E + 255) / 256, 256, 0, stream>>>(ei, deg, E);
    dis_kernel<<<(n + 255) / 256, 256, 0, stream>>>(deg, n);
    gemm1_kernel<<<(n + 31) / 32, 256, 0, stream>>>(x, W1, b1, h, n);
    scatter_kernel<<<(E + 15) / 16, 256, 0, stream>>>(ei, deg, h, lap, E);
    fused2_kernel<<<(n + 31) / 32, 256, 0, stream>>>(h, lap, W20, W21, b2, Wl, bl, out, n);
}